// Round 7
// baseline (476.192 us; speedup 1.0000x reference)
//
#include <hip/hip_runtime.h>

#define B_    64
#define NI    2048
#define DK    16
#define NO    32
#define DOUT  32
#define EPSQ  1e-7f

// ---------- helpers ----------
__device__ __forceinline__ unsigned pack2_bf16(float a, float b) {
    unsigned ua = __float_as_uint(a);
    unsigned ub = __float_as_uint(b);
    ua = (ua + 0x7fffu + ((ua >> 16) & 1u)) >> 16;   // RNE
    ub = (ub + 0x7fffu + ((ub >> 16) & 1u)) >> 16;
    return ua | (ub << 16);
}
__device__ __forceinline__ float bf_lo(unsigned w) { return __uint_as_float(w << 16); }
__device__ __forceinline__ float bf_hi(unsigned w) { return __uint_as_float(w & 0xffff0000u); }

// ============================================================
// FAST PATH
// u_hat layout (bf16/ushort): idx = (((b*NI + i)*4 + j)*NO + o)*8 + e, d = j*8+e
// -> per (b,i): 4*NO rows of 8 ushorts (one uint4 each) = 128 uint4's.
// ============================================================

constexpr int WSTRIDE = 516;   // 512 + 4 pad: one-time LDS read conflicts only

// Produce u_hat = einsum('oidk,bik->boid') once. Block = one i, 512 threads.
// (round-6 version, measured 158 us: coalesced W->LDS staging)
__global__ __launch_bounds__(512)
void compute_uhat(const float* __restrict__ x, const float* __restrict__ W,
                  ushort* __restrict__ U)
{
    __shared__ float Ws[NO * WSTRIDE];   // 66048 B
    __shared__ float xs[B_ * DK];        // 4096 B
    const int i = blockIdx.x;
    const int t = threadIdx.x;

    // stage x[0:64, i, 0:16] (4 KB)
    if (t < 256) {
        const int b = t >> 2, k4 = t & 3;
        float4 v = *(const float4*)(x + ((size_t)b * NI + i) * DK + k4 * 4);
        *(float4*)&xs[b * DK + k4 * 4] = v;
    }

    // stage W[:, i, :, :] (64 KB) coalesced
    #pragma unroll
    for (int jj = 0; jj < 8; ++jj) {
        const int p  = t + 512 * jj;     // 0..4095
        const int oo = p >> 7;           // o
        const int cc = p & 127;          // float4 within o-row
        float4 v = ((const float4*)(W + ((size_t)oo * NI + i) * (DOUT * DK)))[cc];
        *(float4*)&Ws[oo * WSTRIDE + cc * 4] = v;
    }

    const int o  = t & 31;
    const int q  = (t >> 5) & 7;      // d = 4q .. 4q+3
    const int bh = t >> 8;            // 0/1

    __syncthreads();

    float w[64];
    {
        const float* wr = &Ws[o * WSTRIDE + q * 64];
        #pragma unroll
        for (int m = 0; m < 16; ++m) {
            float4 v = *(const float4*)(wr + 4 * m);
            w[4*m+0] = v.x; w[4*m+1] = v.y; w[4*m+2] = v.z; w[4*m+3] = v.w;
        }
    }

    const int j = q >> 1, half = q & 1;

    for (int bb = 0; bb < 32; ++bb) {
        const int b = bh * 32 + bb;
        const float4* xv = (const float4*)&xs[b * DK];
        const float4 x0 = xv[0], x1 = xv[1], x2 = xv[2], x3 = xv[3];

        float acc[4];
        #pragma unroll
        for (int dl = 0; dl < 4; ++dl) {
            const float* wr = &w[dl * 16];
            float a;
            a  = wr[0]  * x0.x + wr[1]  * x0.y + wr[2]  * x0.z + wr[3]  * x0.w;
            a += wr[4]  * x1.x + wr[5]  * x1.y + wr[6]  * x1.z + wr[7]  * x1.w;
            a += wr[8]  * x2.x + wr[9]  * x2.y + wr[10] * x2.z + wr[11] * x2.w;
            a += wr[12] * x3.x + wr[13] * x3.y + wr[14] * x3.z + wr[15] * x3.w;
            acc[dl] = a;
        }

        uint2 pk;
        pk.x = pack2_bf16(acc[0], acc[1]);
        pk.y = pack2_bf16(acc[2], acc[3]);
        const size_t off = ((((size_t)b * NI + i) * 4 + j) * NO + o) * 8 + half * 4;
        *(uint2*)(U + off) = pk;      // 8-byte aligned
    }
}

// ---------- per-i routing math, d-SPLIT: lane=(dh,o) owns 16 d's (2 uint4 rows) ----
template<bool UNI>
__device__ __forceinline__ void proc1(const uint4* cr, const float* vs, float* sacc)
{
    const unsigned cw[8] = { cr[0].x, cr[0].y, cr[0].z, cr[0].w,
                             cr[1].x, cr[1].y, cr[1].z, cr[1].w };
    float u[16];
    #pragma unroll
    for (int m = 0; m < 8; ++m) { u[2*m] = bf_lo(cw[m]); u[2*m+1] = bf_hi(cw[m]); }

    if (UNI) {
        #pragma unroll
        for (int dl = 0; dl < 16; ++dl) sacc[dl] += u[dl];
    } else {
        float p0 = 0.f, p1 = 0.f;
        #pragma unroll
        for (int dl = 0; dl < 16; dl += 2) {
            p0 = fmaf(vs[dl],     u[dl],     p0);
            p1 = fmaf(vs[dl + 1], u[dl + 1], p1);
        }
        float p = p0 + p1;
        p += __shfl_xor(p, 32);          // combine the two d-halves -> full logit

        float mx = p;
        #pragma unroll
        for (int msk = 16; msk >= 1; msk >>= 1) mx = fmaxf(mx, __shfl_xor(mx, msk));
        const float e = __expf(p - mx);
        float ssum = e;
        #pragma unroll
        for (int msk = 16; msk >= 1; msk >>= 1) ssum += __shfl_xor(ssum, msk);
        const float c = e / ssum;

        #pragma unroll
        for (int dl = 0; dl < 16; ++dl) sacc[dl] = fmaf(c, u[dl], sacc[dl]);
    }
}

// One routing iteration as a streaming pass over u_hat.
// Block = (b, i-slab of 128). 256 threads = 4 waves; lane=(dh,o); wave owns 32 i's.
// ~100 VGPR (16-element per-lane arrays) -> 16 waves/CU for latency coverage.
constexpr int BPB = 16;               // i-slabs per b
constexpr int NG  = NI / BPB / 4 / 2; // 16 groups of 2 i per wave

template<bool UNI>
__global__ __launch_bounds__(256)
void routing_stream(const ushort* __restrict__ U, const float* __restrict__ Vsum,
                    float* __restrict__ s_out)
{
    __shared__ float sblk[NO * 33];   // padded: conflict-free lane atomics
    const int t    = threadIdx.x;
    const int b    = blockIdx.x >> 4;
    const int i0   = (blockIdx.x & (BPB - 1)) * (NI / BPB);
    const int lane = t & 63;
    const int o    = lane & 31;
    const int dh   = lane >> 5;       // d-half 0/1
    const int w    = t >> 6;          // wave 0..3

    for (int n = t; n < NO * 33; n += 256) sblk[n] = 0.f;

    float vs[16];
    if (!UNI) {
        const float4* vp = (const float4*)(Vsum + ((size_t)b * NO + o) * DOUT + dh * 16);
        #pragma unroll
        for (int m = 0; m < 4; ++m) {
            float4 v = vp[m];
            vs[4*m+0] = v.x; vs[4*m+1] = v.y; vs[4*m+2] = v.z; vs[4*m+3] = v.w;
        }
    }
    float sacc[16];
    #pragma unroll
    for (int dl = 0; dl < 16; ++dl) sacc[dl] = 0.f;

    __syncthreads();   // sblk zero-init visible

    // rows: R = ((b*NI+i)*4 + j)*NO + o, 1 uint4 per row; lane rows j=2dh,2dh+1
    const int loff = (2 * dh) * NO + o;
    const uint4* up = (const uint4*)U + ((size_t)b * NI + i0 + 2 * w) * (4 * NO) + loff;
    const size_t step = (size_t)8 * 4 * NO;   // advance i by 8

    uint4 cur[4];
    cur[0] = up[0];        cur[1] = up[NO];            // i_a
    cur[2] = up[4 * NO];   cur[3] = up[4 * NO + NO];   // i_b = i_a+1
    up += step;

    for (int g = 0; g < NG; ++g) {
        uint4 nxt[4];
        if (g + 1 < NG) {             // uniform branch
            nxt[0] = up[0];      nxt[1] = up[NO];
            nxt[2] = up[4 * NO]; nxt[3] = up[4 * NO + NO];
            up += step;
        }

        proc1<UNI>(&cur[0], vs, sacc);
        proc1<UNI>(&cur[2], vs, sacc);

        #pragma unroll
        for (int jj = 0; jj < 4; ++jj) cur[jj] = nxt[jj];
    }

    if (UNI) {
        #pragma unroll
        for (int dl = 0; dl < 16; ++dl) sacc[dl] *= 0.03125f;   // c = 1/32
    }

    // block reduce: lanes atomically add their 16 d's (4-way across waves)
    #pragma unroll
    for (int dl = 0; dl < 16; ++dl)
        atomicAdd(&sblk[o * 33 + dh * 16 + dl], sacc[dl]);
    __syncthreads();

    float* sp = s_out + (size_t)b * NO * DOUT;
    for (int n = t; n < NO * DOUT; n += 256) {
        const int oo = n >> 5, dd = n & 31;
        atomicAdd(&sp[n], sblk[oo * 33 + dd]);
    }
}

// v = squash(s); Vsum += v; last iteration writes v to out.
__global__ __launch_bounds__(256)
void squash_update(const float* __restrict__ s, float* __restrict__ Vsum,
                   float* __restrict__ out, int last)
{
    const int tid  = threadIdx.x;
    const int pair = blockIdx.x * 8 + (tid >> 5);
    const int d    = tid & 31;
    const int idx  = pair * DOUT + d;

    const float val = s[idx];
    float sq = val * val;
    #pragma unroll
    for (int msk = 16; msk >= 1; msk >>= 1) sq += __shfl_xor(sq, msk);

    const float scale = sq / (1.f + sq) * rsqrtf(sq + EPSQ);
    const float v = val * scale;

    if (last) out[idx] = v;
    else      Vsum[idx] += v;
}

// ============================================================
// FALLBACK PATH (fused recompute; used if ws too small)
// ============================================================
constexpr int BTILE  = 16;
constexpr int ITILE  = 32;
constexpr int CHUNKS = NI / ITILE;
constexpr int GB     = B_ / BTILE;
constexpr int WROW   = DOUT * DK + 4;

__global__ __launch_bounds__(512)
void routing_pass(const float* __restrict__ x, const float* __restrict__ W,
                  const float* __restrict__ Vsum, float* __restrict__ s_out)
{
    __shared__ float W_s[NO * WROW];
    const int tid   = threadIdx.x;
    const int o     = tid & 31;
    const int bl    = tid >> 5;
    const int chunk = blockIdx.x & (CHUNKS - 1);
    const int gb    = blockIdx.x / CHUNKS;
    const int b     = gb * BTILE + bl;

    float vs[DOUT];
    {
        const float4* vp = (const float4*)(Vsum + (size_t)(b * NO + o) * DOUT);
        #pragma unroll
        for (int qq = 0; qq < 8; ++qq) {
            float4 t2 = vp[qq];
            vs[4*qq+0] = t2.x; vs[4*qq+1] = t2.y; vs[4*qq+2] = t2.z; vs[4*qq+3] = t2.w;
        }
    }
    float sacc[DOUT];
    #pragma unroll
    for (int d = 0; d < DOUT; ++d) sacc[d] = 0.f;

    const int o_ld = tid >> 4;
    const int lpos = tid & 15;

    for (int ii = 0; ii < ITILE; ++ii) {
        const int i = chunk * ITILE + ii;
        __syncthreads();
        const float4* wsrc = (const float4*)W + ((size_t)o_ld * NI + i) * (DOUT * DK / 4);
        #pragma unroll
        for (int jj = 0; jj < 8; ++jj) {
            const int f4pos = lpos + 16 * jj;
            float4 v = wsrc[f4pos];
            *(float4*)&W_s[o_ld * WROW + f4pos * 4] = v;
        }
        __syncthreads();

        const float4* xg = (const float4*)(x + ((size_t)b * NI + i) * DK);
        const float4 xr0 = xg[0], xr1 = xg[1], xr2 = xg[2], xr3 = xg[3];

        float u[DOUT];
        float logit = 0.f;
        const float* wrow = &W_s[o * WROW];
        #pragma unroll
        for (int d = 0; d < DOUT; ++d) {
            const float4 w0 = *(const float4*)(wrow + d * DK + 0);
            const float4 w1 = *(const float4*)(wrow + d * DK + 4);
            const float4 w2 = *(const float4*)(wrow + d * DK + 8);
            const float4 w3 = *(const float4*)(wrow + d * DK + 12);
            float acc;
            acc  = w0.x * xr0.x + w0.y * xr0.y + w0.z * xr0.z + w0.w * xr0.w;
            acc += w1.x * xr1.x + w1.y * xr1.y + w1.z * xr1.z + w1.w * xr1.w;
            acc += w2.x * xr2.x + w2.y * xr2.y + w2.z * xr2.z + w2.w * xr2.w;
            acc += w3.x * xr3.x + w3.y * xr3.y + w3.z * xr3.z + w3.w * xr3.w;
            u[d]  = acc;
            logit = fmaf(vs[d], acc, logit);
        }

        float m = logit;
        #pragma unroll
        for (int msk = 16; msk >= 1; msk >>= 1) m = fmaxf(m, __shfl_xor(m, msk));
        const float e = __expf(logit - m);
        float ssum = e;
        #pragma unroll
        for (int msk = 16; msk >= 1; msk >>= 1) ssum += __shfl_xor(ssum, msk);
        const float c = e / ssum;

        #pragma unroll
        for (int d = 0; d < DOUT; ++d) sacc[d] = fmaf(c, u[d], sacc[d]);
    }

    float* sp = s_out + (size_t)(b * NO + o) * DOUT;
    #pragma unroll
    for (int d = 0; d < DOUT; ++d) atomicAdd(&sp[d], sacc[d]);
}

// ============================================================
extern "C" void kernel_launch(void* const* d_in, const int* in_sizes, int n_in,
                              void* d_out, int out_size, void* d_ws, size_t ws_size,
                              hipStream_t stream)
{
    const float* x = (const float*)d_in[0];   // [B, NI, DK]
    const float* W = (const float*)d_in[1];   // [NO, NI, DOUT, DK]
    float* out = (float*)d_out;               // [B, NO, DOUT]

    float* Vsum = (float*)d_ws;                       // 65536 floats
    float* s    = Vsum + (size_t)B_ * NO * DOUT;      // 65536 floats
    ushort* U   = (ushort*)((char*)d_ws + 512 * 1024);

    const size_t need = 512 * 1024 + (size_t)B_ * NI * NO * DOUT * sizeof(ushort);

    hipMemsetAsync(Vsum, 0, (size_t)B_ * NO * DOUT * sizeof(float), stream);

    if (ws_size >= need) {
        compute_uhat<<<dim3(NI), dim3(512), 0, stream>>>(x, W, U);
        for (int r = 0; r < 3; ++r) {
            hipMemsetAsync(s, 0, (size_t)B_ * NO * DOUT * sizeof(float), stream);
            if (r == 0)
                routing_stream<true><<<dim3(B_ * BPB), dim3(256), 0, stream>>>(U, Vsum, s);
            else
                routing_stream<false><<<dim3(B_ * BPB), dim3(256), 0, stream>>>(U, Vsum, s);
            squash_update<<<dim3(B_ * NO / 8), dim3(256), 0, stream>>>(s, Vsum, out, r == 2);
        }
    } else {
        for (int r = 0; r < 3; ++r) {
            hipMemsetAsync(s, 0, (size_t)B_ * NO * DOUT * sizeof(float), stream);
            routing_pass<<<dim3(GB * CHUNKS), dim3(512), 0, stream>>>(x, W, Vsum, s);
            squash_update<<<dim3(B_ * NO / 8), dim3(256), 0, stream>>>(s, Vsum, out, r == 2);
        }
    }
}